// Round 15
// baseline (111.249 us; speedup 1.0000x reference)
//
#include <hip/hip_runtime.h>
#include <hip/hip_bf16.h>
#include <math.h>

#define BT 48
#define N 1024
#define F 64
#define CIN 64
#define EM 16
#define LRELU_A 0.2f
#define L2E 1.4426950408889634f

typedef short bf16x8 __attribute__((ext_vector_type(8)));   // 8 bf16 = 4 VGPRs
typedef float f32x4  __attribute__((ext_vector_type(4)));
typedef float f32x2  __attribute__((ext_vector_type(2)));
typedef float f32x4e __attribute__((ext_vector_type(4)));
typedef unsigned int u32x4 __attribute__((ext_vector_type(4)));

// exact RTNE float->bf16 bits (k_proj only, off hot path)
__device__ __forceinline__ unsigned short f2bf(float f) {
    unsigned int u = __float_as_uint(f);
    return (unsigned short)((u + 0x7FFFu + ((u >> 16) & 1u)) >> 16);
}

// packed fp32 FMA: acc = x*w + acc (two lanes' worth in one inst)
#define PKFMA(acc, xp, wp) \
    asm("v_pk_fma_f32 %0, %1, %2, %0" : "+v"(acc) : "v"(xp), "v"(wp))

// ------------------------------------------------------------------
// k_proj_misc (R14 "regtile" — unchanged; part of the 110.7us best)
// ------------------------------------------------------------------
__global__ __launch_bounds__(256) void k_proj_misc(
    const float* __restrict__ x, const float* __restrict__ W,
    const float* __restrict__ a,
    const int* __restrict__ adj,
    const float* __restrict__ emb1, const float* __restrict__ emb2,
    const float* __restrict__ a2,
    unsigned short* __restrict__ WhSw,
    float* __restrict__ s1, float* __restrict__ s2,
    unsigned int* __restrict__ adjBits,
    float* __restrict__ f1, float* __restrict__ f2)
{
    const int tid = threadIdx.x;
    const int b   = blockIdx.x;

    __shared__ __align__(16) float sxT[64 * 72];            // x^T, row-swizzled
    __shared__ __align__(16) float sW[64 * 68];             // W [k][c]
    __shared__ __align__(16) unsigned short sT[64 * 80];    // bf16 Wh staging

    const int bt  = b >> 4;
    const int n0  = (b & 15) * 64;
    const size_t grow = (size_t)bt * N + n0;

    {
        const float4* xv = (const float4*)(x + grow * CIN);
        for (int i = tid; i < 1024; i += 256) {
            const float4 v = xv[i];
            const int row = i >> 4, c4 = (i & 15) * 4;
            sxT[(c4 + 0) * 72 + (row ^ (((c4 + 0) & 15) << 2))] = v.x;
            sxT[(c4 + 1) * 72 + (row ^ (((c4 + 1) & 15) << 2))] = v.y;
            sxT[(c4 + 2) * 72 + (row ^ (((c4 + 2) & 15) << 2))] = v.z;
            sxT[(c4 + 3) * 72 + (row ^ (((c4 + 3) & 15) << 2))] = v.w;
        }
        const float4* wv = (const float4*)W;
        for (int i = tid; i < 1024; i += 256) {
            const int k = i >> 4, c4 = (i & 15) * 4;
            *(float4*)&sW[k * 68 + c4] = wv[i];
        }
    }
    __syncthreads();

    const int rg = tid >> 4, cg = tid & 15;
    const int r0 = rg * 4, c0 = cg * 4;

    f32x2 a00 = 0.f, a01 = 0.f, a10 = 0.f, a11 = 0.f;
    f32x2 a20 = 0.f, a21 = 0.f, a30 = 0.f, a31 = 0.f;

#pragma unroll
    for (int k = 0; k < CIN; ++k) {
        const float4 xr  = *(const float4*)&sxT[k * 72 + (r0 ^ ((k & 15) << 2))];
        const float4 wv4 = *(const float4*)&sW[k * 68 + c0];
        f32x2 w01; w01.x = wv4.x; w01.y = wv4.y;
        f32x2 w23; w23.x = wv4.z; w23.y = wv4.w;
        f32x2 xb;
        xb.x = xr.x; xb.y = xr.x;
        PKFMA(a00, xb, w01); PKFMA(a01, xb, w23);
        xb.x = xr.y; xb.y = xr.y;
        PKFMA(a10, xb, w01); PKFMA(a11, xb, w23);
        xb.x = xr.z; xb.y = xr.z;
        PKFMA(a20, xb, w01); PKFMA(a21, xb, w23);
        xb.x = xr.w; xb.y = xr.w;
        PKFMA(a30, xb, w01); PKFMA(a31, xb, w23);
    }

    {
        const float4 aw1 = *(const float4*)&a[c0];
        const float4 aw2 = *(const float4*)&a[F + c0];
        float v1r0 = a00.x*aw1.x + a00.y*aw1.y + a01.x*aw1.z + a01.y*aw1.w;
        float v1r1 = a10.x*aw1.x + a10.y*aw1.y + a11.x*aw1.z + a11.y*aw1.w;
        float v1r2 = a20.x*aw1.x + a20.y*aw1.y + a21.x*aw1.z + a21.y*aw1.w;
        float v1r3 = a30.x*aw1.x + a30.y*aw1.y + a31.x*aw1.z + a31.y*aw1.w;
        float v2r0 = a00.x*aw2.x + a00.y*aw2.y + a01.x*aw2.z + a01.y*aw2.w;
        float v2r1 = a10.x*aw2.x + a10.y*aw2.y + a11.x*aw2.z + a11.y*aw2.w;
        float v2r2 = a20.x*aw2.x + a20.y*aw2.y + a21.x*aw2.z + a21.y*aw2.w;
        float v2r3 = a30.x*aw2.x + a30.y*aw2.y + a31.x*aw2.z + a31.y*aw2.w;
#pragma unroll
        for (int off = 1; off <= 8; off <<= 1) {
            v1r0 += __shfl_xor(v1r0, off, 64); v2r0 += __shfl_xor(v2r0, off, 64);
            v1r1 += __shfl_xor(v1r1, off, 64); v2r1 += __shfl_xor(v2r1, off, 64);
            v1r2 += __shfl_xor(v1r2, off, 64); v2r2 += __shfl_xor(v2r2, off, 64);
            v1r3 += __shfl_xor(v1r3, off, 64); v2r3 += __shfl_xor(v2r3, off, 64);
        }
        if (cg == 0) {
            s1[grow + r0 + 0] = v1r0; s2[grow + r0 + 0] = v2r0;
            s1[grow + r0 + 1] = v1r1; s2[grow + r0 + 1] = v2r1;
            s1[grow + r0 + 2] = v1r2; s2[grow + r0 + 2] = v2r2;
            s1[grow + r0 + 3] = v1r3; s2[grow + r0 + 3] = v2r3;
        }
    }

    sT[(c0+0)*80 + r0+0] = f2bf(a00.x); sT[(c0+1)*80 + r0+0] = f2bf(a00.y);
    sT[(c0+2)*80 + r0+0] = f2bf(a01.x); sT[(c0+3)*80 + r0+0] = f2bf(a01.y);
    sT[(c0+0)*80 + r0+1] = f2bf(a10.x); sT[(c0+1)*80 + r0+1] = f2bf(a10.y);
    sT[(c0+2)*80 + r0+1] = f2bf(a11.x); sT[(c0+3)*80 + r0+1] = f2bf(a11.y);
    sT[(c0+0)*80 + r0+2] = f2bf(a20.x); sT[(c0+1)*80 + r0+2] = f2bf(a20.y);
    sT[(c0+2)*80 + r0+2] = f2bf(a21.x); sT[(c0+3)*80 + r0+2] = f2bf(a21.y);
    sT[(c0+0)*80 + r0+3] = f2bf(a30.x); sT[(c0+1)*80 + r0+3] = f2bf(a30.y);
    sT[(c0+2)*80 + r0+3] = f2bf(a31.x); sT[(c0+3)*80 + r0+3] = f2bf(a31.y);
    __syncthreads();

    {
        const int ff = tid >> 2, qq = tid & 3;
        const int slot = (qq + ff) & 3;
        const int nb0 = (b & 15) * 2;
#pragma unroll
        for (int nbL = 0; nbL < 2; ++nbL) {
            const size_t dst = ((size_t)(bt * 32 + nb0 + nbL) * 64 + ff) * 32 + slot * 8;
            *(uint4*)&WhSw[dst] = *(const uint4*)&sT[ff * 80 + nbL * 32 + qq * 8];
        }
    }

    if (b < 128) {
        const int idx = b * 256 + tid;
        const int r = idx >> 5, w32 = idx & 31;
        const int* p = adj + (size_t)r * N + w32 * 32;
        unsigned int m = 0;
#pragma unroll
        for (int j = 0; j < 32; ++j) m |= (p[j] > 0 ? 1u : 0u) << j;
        adjBits[idx] = m;
    } else if (b < 132) {
        const int n = (b - 128) * 256 + tid;
        float v1 = 0.f, v2 = 0.f;
#pragma unroll
        for (int k = 0; k < EM; ++k) {
            v1 = fmaf(emb1[n * EM + k], a2[k], v1);
            v2 = fmaf(emb2[n * EM + k], a2[EM + k], v2);
        }
        f1[n] = v1; f2[n] = v2;
    }
}

// ------------------------------------------------------------------
// k_attn round 22 "mfma-lsum": R14 structure + two volume cuts:
//  1. Row denominators via ONES-COLUMN MFMA on the idle matrix pipe
//     (MfmaUtil was 5%): accL = sum_k P[r][k] accumulated by 4 extra
//     MFMAs/chunk with a constant all-1.0 bf16 B-fragment. Kills 256
//     scalar lsum adds + 6 epilogue shuffles per thread (PAIRPK 9->7
//     inst / 2 elems). rinv_reg = 1/accL[reg] (same D-layout rows
//     q*4+reg as acc0..3). Denominator now sums the SAME bf16 p that
//     feeds PV (errors cancel over ~512 terms, rel ~1e-4).
//  2. Register-PIN the P/Q banks after MAKE_AFR (empty asm "+v"):
//     R13's VGPR=76 proved the compiler sinks bank loads into uses,
//     collapsing the ping-pong; the pin forces issue >=450cyc early.
// ------------------------------------------------------------------

#define PAIRPK(x1p, x2p, bit, dest) do {                                   \
    f32x2 m1_, m2_;                                                        \
    asm("v_pk_mul_f32 %0, %1, %2" : "=v"(m1_) : "v"(x1p), "v"(E1p));       \
    asm("v_pk_mul_f32 %0, %1, %2" : "=v"(m2_) : "v"(x2p), "v"(E2p));       \
    float p0_ = fmaxf(m1_.x, m2_.x);                                       \
    float p1_ = fmaxf(m1_.y, m2_.y);                                       \
    p0_ = ((mb_ >> (bit)) & 1u) ? p0_ : 0.f;                               \
    p1_ = ((mb_ >> ((bit) + 1)) & 1u) ? p1_ : 0.f;                         \
    unsigned int pk_;                                                      \
    asm("v_cvt_pk_bf16_f32 %0, %1, %2" : "=v"(pk_) : "v"(p0_), "v"(p1_)); \
    dest = pk_;                                                            \
} while (0)

#define MAKE_ONE(ch, ks, Avar, abword) do {                                \
    const int jb_ = (ch) * 128 + (ks) * 32 + q * 8;                        \
    const f32x4e x1a_ = *(const f32x4e*)&sX1[jb_];                         \
    const f32x4e x1b_ = *(const f32x4e*)&sX1[jb_ + 4];                     \
    const f32x4e x2a_ = *(const f32x4e*)&sX2[jb_];                         \
    const f32x4e x2b_ = *(const f32x4e*)&sX2[jb_ + 4];                     \
    const unsigned int mb_ = ((abword) >> (q * 8)) & 0xFFu;                \
    unsigned int u0_, u1_, u2_, u3_;                                       \
    PAIRPK(__builtin_shufflevector(x1a_, x1a_, 0, 1),                      \
           __builtin_shufflevector(x2a_, x2a_, 0, 1), 0, u0_);             \
    PAIRPK(__builtin_shufflevector(x1a_, x1a_, 2, 3),                      \
           __builtin_shufflevector(x2a_, x2a_, 2, 3), 2, u1_);             \
    PAIRPK(__builtin_shufflevector(x1b_, x1b_, 0, 1),                      \
           __builtin_shufflevector(x2b_, x2b_, 0, 1), 4, u2_);             \
    PAIRPK(__builtin_shufflevector(x1b_, x1b_, 2, 3),                      \
           __builtin_shufflevector(x2b_, x2b_, 2, 3), 6, u3_);             \
    u32x4 av_; av_.x = u0_; av_.y = u1_; av_.z = u2_; av_.w = u3_;         \
    Avar = __builtin_bit_cast(bf16x8, av_);                                \
} while (0)

#define MAKE_AFR(ch, abv, A0, A1, A2, A3) do {                             \
    MAKE_ONE(ch, 0, A0, abv.x);                                            \
    MAKE_ONE(ch, 1, A1, abv.y);                                            \
    MAKE_ONE(ch, 2, A2, abv.z);                                            \
    MAKE_ONE(ch, 3, A3, abv.w);                                            \
} while (0)

#define LB(v, ch, ks, ct)                                                  \
    v = *(const bf16x8*)(gBc + (size_t)(ch) * 16384 + (ks) * 4096 +        \
        ((ct) * 16 + m15) * 64 + slotoff)

#define LOAD8(B0, B1, B2, B3, B4, B5, B6, B7, ch, ct0, ct1) do {           \
    LB(B0, ch, 0, ct0); LB(B1, ch, 1, ct0);                                \
    LB(B2, ch, 2, ct0); LB(B3, ch, 3, ct0);                                \
    LB(B4, ch, 0, ct1); LB(B5, ch, 1, ct1);                                \
    LB(B6, ch, 2, ct1); LB(B7, ch, 3, ct1);                                \
} while (0)

// force the bank resident in VGPRs at this point (defeats load sinking)
#define PIN8(B0, B1, B2, B3, B4, B5, B6, B7)                               \
    asm volatile("" : "+v"(B0), "+v"(B1), "+v"(B2), "+v"(B3),              \
                      "+v"(B4), "+v"(B5), "+v"(B6), "+v"(B7))

#define MFMA8(B0, B1, B2, B3, B4, B5, B6, B7, c0, c1) do {                 \
    acc##c0 = __builtin_amdgcn_mfma_f32_16x16x32_bf16(fA0, B0, acc##c0, 0, 0, 0); \
    acc##c0 = __builtin_amdgcn_mfma_f32_16x16x32_bf16(fA1, B1, acc##c0, 0, 0, 0); \
    acc##c0 = __builtin_amdgcn_mfma_f32_16x16x32_bf16(fA2, B2, acc##c0, 0, 0, 0); \
    acc##c0 = __builtin_amdgcn_mfma_f32_16x16x32_bf16(fA3, B3, acc##c0, 0, 0, 0); \
    acc##c1 = __builtin_amdgcn_mfma_f32_16x16x32_bf16(fA0, B4, acc##c1, 0, 0, 0); \
    acc##c1 = __builtin_amdgcn_mfma_f32_16x16x32_bf16(fA1, B5, acc##c1, 0, 0, 0); \
    acc##c1 = __builtin_amdgcn_mfma_f32_16x16x32_bf16(fA2, B6, acc##c1, 0, 0, 0); \
    acc##c1 = __builtin_amdgcn_mfma_f32_16x16x32_bf16(fA3, B7, acc##c1, 0, 0, 0); \
} while (0)

// row-denominator accumulation on the (idle) matrix pipe
#define MFMA_L() do {                                                      \
    accL = __builtin_amdgcn_mfma_f32_16x16x32_bf16(fA0, Bones, accL, 0, 0, 0); \
    accL = __builtin_amdgcn_mfma_f32_16x16x32_bf16(fA1, Bones, accL, 0, 0, 0); \
    accL = __builtin_amdgcn_mfma_f32_16x16x32_bf16(fA2, Bones, accL, 0, 0, 0); \
    accL = __builtin_amdgcn_mfma_f32_16x16x32_bf16(fA3, Bones, accL, 0, 0, 0); \
} while (0)

#define CHUNK_MID(ch) do {                                                 \
    LOAD8(Q0, Q1, Q2, Q3, Q4, Q5, Q6, Q7, ch, 2, 3);                       \
    const uint4 abv_ = abRow4[ch];                                         \
    MAKE_AFR(ch, abv_, fA0, fA1, fA2, fA3);                                \
    PIN8(Q0, Q1, Q2, Q3, Q4, Q5, Q6, Q7);                                  \
    PIN8(P0, P1, P2, P3, P4, P5, P6, P7);                                  \
    MFMA8(P0, P1, P2, P3, P4, P5, P6, P7, 0, 1);                           \
    LOAD8(P0, P1, P2, P3, P4, P5, P6, P7, (ch) + 1, 0, 1);                 \
    MFMA8(Q0, Q1, Q2, Q3, Q4, Q5, Q6, Q7, 2, 3);                           \
    MFMA_L();                                                              \
} while (0)

#define CHUNK_LAST(ch) do {                                                \
    LOAD8(Q0, Q1, Q2, Q3, Q4, Q5, Q6, Q7, ch, 2, 3);                       \
    const uint4 abv_ = abRow4[ch];                                         \
    MAKE_AFR(ch, abv_, fA0, fA1, fA2, fA3);                                \
    PIN8(Q0, Q1, Q2, Q3, Q4, Q5, Q6, Q7);                                  \
    PIN8(P0, P1, P2, P3, P4, P5, P6, P7);                                  \
    MFMA8(P0, P1, P2, P3, P4, P5, P6, P7, 0, 1);                           \
    MFMA8(Q0, Q1, Q2, Q3, Q4, Q5, Q6, Q7, 2, 3);                           \
    MFMA_L();                                                              \
} while (0)

#define EPI(ct, accv) do {                                                 \
    float h0_ = accv.x * rinv0, h1_ = accv.y * rinv1,                      \
          h2_ = accv.z * rinv2, h3_ = accv.w * rinv3;                      \
    h0_ = (h0_ > 0.f) ? h0_ : (__expf(h0_) - 1.f);                         \
    h1_ = (h1_ > 0.f) ? h1_ : (__expf(h1_) - 1.f);                         \
    h2_ = (h2_ > 0.f) ? h2_ : (__expf(h2_) - 1.f);                         \
    h3_ = (h3_ > 0.f) ? h3_ : (__expf(h3_) - 1.f);                         \
    float* op_ = out + (size_t)(bt * N + i0 + w * 16 + q * 4) * F          \
                 + (ct) * 16 + m15;                                        \
    op_[0 * F] = h0_; op_[1 * F] = h1_; op_[2 * F] = h2_; op_[3 * F] = h3_;\
} while (0)

__global__ __launch_bounds__(256, 3) void k_attn(
    const unsigned int* __restrict__ adjBits,
    const unsigned short* __restrict__ WhSw,
    const float* __restrict__ s1, const float* __restrict__ s2,
    const float* __restrict__ f1v, const float* __restrict__ f2v,
    float* __restrict__ out)
{
    __shared__ __align__(16) float sX1[N];                  // 2^c   (scaled domain)
    __shared__ __align__(16) float sX2[N];                  // 2^.2c
    __shared__ float sWmax[4];

    const int tid  = threadIdx.x;
    const int xcd = blockIdx.x & 7;                         // XCD swizzle: 6 bt/XCD
    const int idx = blockIdx.x >> 3;
    const int bt  = xcd * 6 + (idx >> 4);
    const int i0  = (idx & 15) * 64;
    const int lane = tid & 63;
    const int w    = tid >> 6;
    const int q    = lane >> 4;
    const int m15  = lane & 15;

    const int growq = i0 + w * 16 + m15;
    const uint4* abRow4 = (const uint4*)(adjBits + (size_t)growq * 32);
    const float rraw = s1[bt * N + growq] + f1v[growq];

    // stage X1/X2 and track block max of c (scaled by log2e)
    float cmax = -1e30f;
    for (int j = tid; j < N; j += 256) {
        const float c = (s2[bt * N + j] + f2v[j]) * L2E;
        sX1[j] = exp2f(c);
        sX2[j] = exp2f(LRELU_A * c);
        cmax = fmaxf(cmax, c);
    }
#pragma unroll
    for (int off = 32; off >= 1; off >>= 1) cmax = fmaxf(cmax, __shfl_xor(cmax, off, 64));
    if (lane == 0) sWmax[w] = cmax;
    __syncthreads();
    const float mx = fmaxf(fmaxf(sWmax[0], sWmax[1]), fmaxf(sWmax[2], sWmax[3]));

    const float r    = rraw * L2E;                          // scaled domain
    const float smx  = r + mx;
    const float mhat = fmaxf(smx, LRELU_A * smx);           // >= every scaled e in row
    const float E1 = exp2f(r - mhat);
    const float E2 = exp2f(LRELU_A * r - mhat);
    f32x2 E1p; E1p.x = E1; E1p.y = E1;
    f32x2 E2p; E2p.x = E2; E2p.y = E2;

    const char* gBc = (const char*)(WhSw + (size_t)bt * 65536);
    const int slotoff = ((q + m15) & 3) * 16;               // XOR-swizzled slot

    // constant all-ones bf16 B-fragment for the denominator MFMA
    u32x4 ob_; ob_.x = 0x3F803F80u; ob_.y = 0x3F803F80u;
    ob_.z = 0x3F803F80u; ob_.w = 0x3F803F80u;
    const bf16x8 Bones = __builtin_bit_cast(bf16x8, ob_);

    f32x4 acc0 = 0.f, acc1 = 0.f, acc2 = 0.f, acc3 = 0.f;
    f32x4 accL = 0.f;                                       // row denominators
    bf16x8 fA0, fA1, fA2, fA3;
    bf16x8 P0, P1, P2, P3, P4, P5, P6, P7;                  // bank P (32 VGPR)
    bf16x8 Q0, Q1, Q2, Q3, Q4, Q5, Q6, Q7;                  // bank Q (32 VGPR)

    LOAD8(P0, P1, P2, P3, P4, P5, P6, P7, 0, 0, 1);

    CHUNK_MID(0); CHUNK_MID(1); CHUNK_MID(2); CHUNK_MID(3);
    CHUNK_MID(4); CHUNK_MID(5); CHUNK_MID(6); CHUNK_LAST(7);

    // accL[reg] = rowsum(q*4+reg) — same rows as acc0..3's reg index
    const float rinv0 = 1.f / accL.x;
    const float rinv1 = 1.f / accL.y;
    const float rinv2 = 1.f / accL.z;
    const float rinv3 = 1.f / accL.w;

    EPI(0, acc0); EPI(1, acc1); EPI(2, acc2); EPI(3, acc3);
}

// ------------------------------------------------------------------
extern "C" void kernel_launch(void* const* d_in, const int* in_sizes, int n_in,
                              void* d_out, int out_size, void* d_ws, size_t ws_size,
                              hipStream_t stream)
{
    const float* x    = (const float*)d_in[0];
    const int*   adj  = (const int*)  d_in[1];
    const float* emb1 = (const float*)d_in[2];
    const float* emb2 = (const float*)d_in[3];
    const float* W    = (const float*)d_in[4];
    const float* a    = (const float*)d_in[5];
    const float* a2   = (const float*)d_in[6];
    float* out = (float*)d_out;

    unsigned short* WhSw = (unsigned short*)d_ws;             // 6.29 MB
    float* s1 = (float*)(WhSw + (size_t)BT * 65536);
    float* s2 = s1 + BT * N;
    float* f1 = s2 + BT * N;
    float* f2 = f1 + N;
    unsigned int* adjBits = (unsigned int*)(f2 + N);          // 128 KB

    hipLaunchKernelGGL(k_proj_misc, dim3(768), dim3(256), 0, stream,
                       x, W, a, adj, emb1, emb2, a2, WhSw, s1, s2, adjBits, f1, f2);
    hipLaunchKernelGGL(k_attn, dim3(BT * 16), dim3(256), 0, stream,
                       adjBits, WhSw, s1, s2, f1, f2, out);
}

// Round 16
// 109.480 us; speedup vs baseline: 1.0162x; 1.0162x over previous
//
#include <hip/hip_runtime.h>
#include <hip/hip_bf16.h>
#include <math.h>

#define BT 48
#define N 1024
#define F 64
#define CIN 64
#define EM 16
#define LRELU_A 0.2f
#define L2E 1.4426950408889634f

typedef short bf16x8 __attribute__((ext_vector_type(8)));   // 8 bf16 = 4 VGPRs
typedef float f32x4  __attribute__((ext_vector_type(4)));
typedef float f32x2  __attribute__((ext_vector_type(2)));
typedef float f32x4e __attribute__((ext_vector_type(4)));
typedef unsigned int u32x4 __attribute__((ext_vector_type(4)));

// exact RTNE float->bf16 bits
__device__ __forceinline__ unsigned short f2bf(float f) {
    unsigned int u = __float_as_uint(f);
    return (unsigned short)((u + 0x7FFFu + ((u >> 16) & 1u)) >> 16);
}

// packed fp32 FMA: acc = x*w + acc
#define PKFMA(acc, xp, wp) \
    asm("v_pk_fma_f32 %0, %1, %2, %0" : "+v"(acc) : "v"(xp), "v"(wp))

// ------------------------------------------------------------------
// k_proj_misc round 23 "lean-LDS": R14 regtile with pure overhead
// removal (NO redundant work added, unlike R12's failed TLP try):
//  - sxT stride 72 -> 68 (swizzle XOR operand is a multiple of 4
//    rows; stride only scales the row base, 272B rows stay 16B-
//    aligned; 2-way b128 bank aliasing, free per m136)
//  - sT DELETED: thread (rg,cg) owns rows r0..r0+3 (r0&7 in {0,4})
//    of cols c0..c0+3. In WhSw layout [nb][f][slot(qq+f)][t=r&7],
//    those 4 rows are one aligned 8B ushort4 -> store reg->global
//    directly, second __syncthreads dropped.
//  LDS 46.1 -> 34.8 KB => 4 blocks/CU (16 waves, +33% TLP).
// ------------------------------------------------------------------
__global__ __launch_bounds__(256) void k_proj_misc(
    const float* __restrict__ x, const float* __restrict__ W,
    const float* __restrict__ a,
    const int* __restrict__ adj,
    const float* __restrict__ emb1, const float* __restrict__ emb2,
    const float* __restrict__ a2,
    unsigned short* __restrict__ WhSw,
    float* __restrict__ s1, float* __restrict__ s2,
    unsigned int* __restrict__ adjBits,
    float* __restrict__ f1, float* __restrict__ f2)
{
    const int tid = threadIdx.x;
    const int b   = blockIdx.x;

    __shared__ __align__(16) float sxT[64 * 68];            // x^T, row-swizzled
    __shared__ __align__(16) float sW[64 * 68];             // W [k][c]

    const int bt  = b >> 4;
    const int n0  = (b & 15) * 64;
    const size_t grow = (size_t)bt * N + n0;

    {
        const float4* xv = (const float4*)(x + grow * CIN);
        for (int i = tid; i < 1024; i += 256) {
            const float4 v = xv[i];
            const int row = i >> 4, c4 = (i & 15) * 4;
            sxT[(c4 + 0) * 68 + (row ^ (((c4 + 0) & 15) << 2))] = v.x;
            sxT[(c4 + 1) * 68 + (row ^ (((c4 + 1) & 15) << 2))] = v.y;
            sxT[(c4 + 2) * 68 + (row ^ (((c4 + 2) & 15) << 2))] = v.z;
            sxT[(c4 + 3) * 68 + (row ^ (((c4 + 3) & 15) << 2))] = v.w;
        }
        const float4* wv = (const float4*)W;
        for (int i = tid; i < 1024; i += 256) {
            const int k = i >> 4, c4 = (i & 15) * 4;
            *(float4*)&sW[k * 68 + c4] = wv[i];
        }
    }
    __syncthreads();

    const int rg = tid >> 4, cg = tid & 15;
    const int r0 = rg * 4, c0 = cg * 4;

    f32x2 a00 = 0.f, a01 = 0.f, a10 = 0.f, a11 = 0.f;
    f32x2 a20 = 0.f, a21 = 0.f, a30 = 0.f, a31 = 0.f;

#pragma unroll
    for (int k = 0; k < CIN; ++k) {
        const float4 xr  = *(const float4*)&sxT[k * 68 + (r0 ^ ((k & 15) << 2))];
        const float4 wv4 = *(const float4*)&sW[k * 68 + c0];
        f32x2 w01; w01.x = wv4.x; w01.y = wv4.y;
        f32x2 w23; w23.x = wv4.z; w23.y = wv4.w;
        f32x2 xb;
        xb.x = xr.x; xb.y = xr.x;
        PKFMA(a00, xb, w01); PKFMA(a01, xb, w23);
        xb.x = xr.y; xb.y = xr.y;
        PKFMA(a10, xb, w01); PKFMA(a11, xb, w23);
        xb.x = xr.z; xb.y = xr.z;
        PKFMA(a20, xb, w01); PKFMA(a21, xb, w23);
        xb.x = xr.w; xb.y = xr.w;
        PKFMA(a30, xb, w01); PKFMA(a31, xb, w23);
    }

    // s1/s2: thread-local 4-col dot + 16-lane (cg) butterfly
    {
        const float4 aw1 = *(const float4*)&a[c0];
        const float4 aw2 = *(const float4*)&a[F + c0];
        float v1r0 = a00.x*aw1.x + a00.y*aw1.y + a01.x*aw1.z + a01.y*aw1.w;
        float v1r1 = a10.x*aw1.x + a10.y*aw1.y + a11.x*aw1.z + a11.y*aw1.w;
        float v1r2 = a20.x*aw1.x + a20.y*aw1.y + a21.x*aw1.z + a21.y*aw1.w;
        float v1r3 = a30.x*aw1.x + a30.y*aw1.y + a31.x*aw1.z + a31.y*aw1.w;
        float v2r0 = a00.x*aw2.x + a00.y*aw2.y + a01.x*aw2.z + a01.y*aw2.w;
        float v2r1 = a10.x*aw2.x + a10.y*aw2.y + a11.x*aw2.z + a11.y*aw2.w;
        float v2r2 = a20.x*aw2.x + a20.y*aw2.y + a21.x*aw2.z + a21.y*aw2.w;
        float v2r3 = a30.x*aw2.x + a30.y*aw2.y + a31.x*aw2.z + a31.y*aw2.w;
#pragma unroll
        for (int off = 1; off <= 8; off <<= 1) {
            v1r0 += __shfl_xor(v1r0, off, 64); v2r0 += __shfl_xor(v2r0, off, 64);
            v1r1 += __shfl_xor(v1r1, off, 64); v2r1 += __shfl_xor(v2r1, off, 64);
            v1r2 += __shfl_xor(v1r2, off, 64); v2r2 += __shfl_xor(v2r2, off, 64);
            v1r3 += __shfl_xor(v1r3, off, 64); v2r3 += __shfl_xor(v2r3, off, 64);
        }
        if (cg == 0) {
            s1[grow + r0 + 0] = v1r0; s2[grow + r0 + 0] = v2r0;
            s1[grow + r0 + 1] = v1r1; s2[grow + r0 + 1] = v2r1;
            s1[grow + r0 + 2] = v1r2; s2[grow + r0 + 2] = v2r2;
            s1[grow + r0 + 3] = v1r3; s2[grow + r0 + 3] = v2r3;
        }
    }

    // direct reg->global bf16 Wh stores (old path: sT + barrier + uint4)
    // rows r0..r0+3 of col c => WhSw[((bt*32+nb)*64+c)*32 + slot*8 + t0 .. +3]
    {
        const int nb = (b & 15) * 2 + (r0 >> 5);
        const int qq = (r0 >> 3) & 3;
        const int t0 = r0 & 7;
        const size_t base = ((size_t)(bt * 32 + nb) * 64) * 32;
#define STCOL(cc, v0, v1, v2, v3) do {                                      \
        const int c_ = c0 + (cc);                                           \
        const size_t off_ = base + (size_t)c_ * 32 + ((qq + c_) & 3) * 8 + t0; \
        ushort4 pv_;                                                        \
        pv_.x = f2bf(v0); pv_.y = f2bf(v1);                                 \
        pv_.z = f2bf(v2); pv_.w = f2bf(v3);                                 \
        *(ushort4*)&WhSw[off_] = pv_;                                       \
    } while (0)
        STCOL(0, a00.x, a10.x, a20.x, a30.x);
        STCOL(1, a00.y, a10.y, a20.y, a30.y);
        STCOL(2, a01.x, a11.x, a21.x, a31.x);
        STCOL(3, a01.y, a11.y, a21.y, a31.y);
#undef STCOL
    }

    if (b < 128) {
        const int idx = b * 256 + tid;
        const int r = idx >> 5, w32 = idx & 31;
        const int* p = adj + (size_t)r * N + w32 * 32;
        unsigned int m = 0;
#pragma unroll
        for (int j = 0; j < 32; ++j) m |= (p[j] > 0 ? 1u : 0u) << j;
        adjBits[idx] = m;
    } else if (b < 132) {
        const int n = (b - 128) * 256 + tid;
        float v1 = 0.f, v2 = 0.f;
#pragma unroll
        for (int k = 0; k < EM; ++k) {
            v1 = fmaf(emb1[n * EM + k], a2[k], v1);
            v2 = fmaf(emb2[n * EM + k], a2[EM + k], v2);
        }
        f1[n] = v1; f2[n] = v2;
    }
}

// ------------------------------------------------------------------
// k_attn: R14-exact (the 110.7us best) — regB-pp + packed PAIRPK.
// ------------------------------------------------------------------

#define PAIRPK(x1p, x2p, bit, dest) do {                                   \
    f32x2 m1_, m2_;                                                        \
    asm("v_pk_mul_f32 %0, %1, %2" : "=v"(m1_) : "v"(x1p), "v"(E1p));       \
    asm("v_pk_mul_f32 %0, %1, %2" : "=v"(m2_) : "v"(x2p), "v"(E2p));       \
    float p0_ = fmaxf(m1_.x, m2_.x);                                       \
    float p1_ = fmaxf(m1_.y, m2_.y);                                       \
    p0_ = ((mb_ >> (bit)) & 1u) ? p0_ : 0.f;                               \
    p1_ = ((mb_ >> ((bit) + 1)) & 1u) ? p1_ : 0.f;                         \
    lsum += p0_ + p1_;                                                     \
    unsigned int pk_;                                                      \
    asm("v_cvt_pk_bf16_f32 %0, %1, %2" : "=v"(pk_) : "v"(p0_), "v"(p1_)); \
    dest = pk_;                                                            \
} while (0)

#define MAKE_ONE(ch, ks, Avar, abword) do {                                \
    const int jb_ = (ch) * 128 + (ks) * 32 + q * 8;                        \
    const f32x4e x1a_ = *(const f32x4e*)&sX1[jb_];                         \
    const f32x4e x1b_ = *(const f32x4e*)&sX1[jb_ + 4];                     \
    const f32x4e x2a_ = *(const f32x4e*)&sX2[jb_];                         \
    const f32x4e x2b_ = *(const f32x4e*)&sX2[jb_ + 4];                     \
    const unsigned int mb_ = ((abword) >> (q * 8)) & 0xFFu;                \
    unsigned int u0_, u1_, u2_, u3_;                                       \
    PAIRPK(__builtin_shufflevector(x1a_, x1a_, 0, 1),                      \
           __builtin_shufflevector(x2a_, x2a_, 0, 1), 0, u0_);             \
    PAIRPK(__builtin_shufflevector(x1a_, x1a_, 2, 3),                      \
           __builtin_shufflevector(x2a_, x2a_, 2, 3), 2, u1_);             \
    PAIRPK(__builtin_shufflevector(x1b_, x1b_, 0, 1),                      \
           __builtin_shufflevector(x2b_, x2b_, 0, 1), 4, u2_);             \
    PAIRPK(__builtin_shufflevector(x1b_, x1b_, 2, 3),                      \
           __builtin_shufflevector(x2b_, x2b_, 2, 3), 6, u3_);             \
    u32x4 av_; av_.x = u0_; av_.y = u1_; av_.z = u2_; av_.w = u3_;         \
    Avar = __builtin_bit_cast(bf16x8, av_);                                \
} while (0)

#define MAKE_AFR(ch, abv, A0, A1, A2, A3) do {                             \
    MAKE_ONE(ch, 0, A0, abv.x);                                            \
    MAKE_ONE(ch, 1, A1, abv.y);                                            \
    MAKE_ONE(ch, 2, A2, abv.z);                                            \
    MAKE_ONE(ch, 3, A3, abv.w);                                            \
} while (0)

#define LB(v, ch, ks, ct)                                                  \
    v = *(const bf16x8*)(gBc + (size_t)(ch) * 16384 + (ks) * 4096 +        \
        ((ct) * 16 + m15) * 64 + slotoff)

#define LOAD8(B0, B1, B2, B3, B4, B5, B6, B7, ch, ct0, ct1) do {           \
    LB(B0, ch, 0, ct0); LB(B1, ch, 1, ct0);                                \
    LB(B2, ch, 2, ct0); LB(B3, ch, 3, ct0);                                \
    LB(B4, ch, 0, ct1); LB(B5, ch, 1, ct1);                                \
    LB(B6, ch, 2, ct1); LB(B7, ch, 3, ct1);                                \
} while (0)

#define MFMA8(B0, B1, B2, B3, B4, B5, B6, B7, c0, c1) do {                 \
    acc##c0 = __builtin_amdgcn_mfma_f32_16x16x32_bf16(fA0, B0, acc##c0, 0, 0, 0); \
    acc##c0 = __builtin_amdgcn_mfma_f32_16x16x32_bf16(fA1, B1, acc##c0, 0, 0, 0); \
    acc##c0 = __builtin_amdgcn_mfma_f32_16x16x32_bf16(fA2, B2, acc##c0, 0, 0, 0); \
    acc##c0 = __builtin_amdgcn_mfma_f32_16x16x32_bf16(fA3, B3, acc##c0, 0, 0, 0); \
    acc##c1 = __builtin_amdgcn_mfma_f32_16x16x32_bf16(fA0, B4, acc##c1, 0, 0, 0); \
    acc##c1 = __builtin_amdgcn_mfma_f32_16x16x32_bf16(fA1, B5, acc##c1, 0, 0, 0); \
    acc##c1 = __builtin_amdgcn_mfma_f32_16x16x32_bf16(fA2, B6, acc##c1, 0, 0, 0); \
    acc##c1 = __builtin_amdgcn_mfma_f32_16x16x32_bf16(fA3, B7, acc##c1, 0, 0, 0); \
} while (0)

#define CHUNK_MID(ch) do {                                                 \
    LOAD8(Q0, Q1, Q2, Q3, Q4, Q5, Q6, Q7, ch, 2, 3);                       \
    const uint4 abv_ = abRow4[ch];                                         \
    MAKE_AFR(ch, abv_, fA0, fA1, fA2, fA3);                                \
    MFMA8(P0, P1, P2, P3, P4, P5, P6, P7, 0, 1);                           \
    LOAD8(P0, P1, P2, P3, P4, P5, P6, P7, (ch) + 1, 0, 1);                 \
    MFMA8(Q0, Q1, Q2, Q3, Q4, Q5, Q6, Q7, 2, 3);                           \
} while (0)

#define CHUNK_LAST(ch) do {                                                \
    LOAD8(Q0, Q1, Q2, Q3, Q4, Q5, Q6, Q7, ch, 2, 3);                       \
    const uint4 abv_ = abRow4[ch];                                         \
    MAKE_AFR(ch, abv_, fA0, fA1, fA2, fA3);                                \
    MFMA8(P0, P1, P2, P3, P4, P5, P6, P7, 0, 1);                           \
    MFMA8(Q0, Q1, Q2, Q3, Q4, Q5, Q6, Q7, 2, 3);                           \
} while (0)

#define EPI(ct, accv) do {                                                 \
    float h0_ = accv.x * rinv0, h1_ = accv.y * rinv1,                      \
          h2_ = accv.z * rinv2, h3_ = accv.w * rinv3;                      \
    h0_ = (h0_ > 0.f) ? h0_ : (__expf(h0_) - 1.f);                         \
    h1_ = (h1_ > 0.f) ? h1_ : (__expf(h1_) - 1.f);                         \
    h2_ = (h2_ > 0.f) ? h2_ : (__expf(h2_) - 1.f);                         \
    h3_ = (h3_ > 0.f) ? h3_ : (__expf(h3_) - 1.f);                         \
    float* op_ = out + (size_t)(bt * N + i0 + w * 16 + q * 4) * F          \
                 + (ct) * 16 + m15;                                        \
    op_[0 * F] = h0_; op_[1 * F] = h1_; op_[2 * F] = h2_; op_[3 * F] = h3_;\
} while (0)

__global__ __launch_bounds__(256, 3) void k_attn(
    const unsigned int* __restrict__ adjBits,
    const unsigned short* __restrict__ WhSw,
    const float* __restrict__ s1, const float* __restrict__ s2,
    const float* __restrict__ f1v, const float* __restrict__ f2v,
    float* __restrict__ out)
{
    __shared__ __align__(16) float sX1[N];                  // 2^c   (scaled domain)
    __shared__ __align__(16) float sX2[N];                  // 2^.2c
    __shared__ float sWmax[4];

    const int tid  = threadIdx.x;
    const int xcd = blockIdx.x & 7;                         // XCD swizzle: 6 bt/XCD
    const int idx = blockIdx.x >> 3;
    const int bt  = xcd * 6 + (idx >> 4);
    const int i0  = (idx & 15) * 64;
    const int lane = tid & 63;
    const int w    = tid >> 6;
    const int q    = lane >> 4;
    const int m15  = lane & 15;

    const int growq = i0 + w * 16 + m15;
    const uint4* abRow4 = (const uint4*)(adjBits + (size_t)growq * 32);
    const float rraw = s1[bt * N + growq] + f1v[growq];

    // stage X1/X2 and track block max of c (scaled by log2e)
    float cmax = -1e30f;
    for (int j = tid; j < N; j += 256) {
        const float c = (s2[bt * N + j] + f2v[j]) * L2E;
        sX1[j] = exp2f(c);
        sX2[j] = exp2f(LRELU_A * c);
        cmax = fmaxf(cmax, c);
    }
#pragma unroll
    for (int off = 32; off >= 1; off >>= 1) cmax = fmaxf(cmax, __shfl_xor(cmax, off, 64));
    if (lane == 0) sWmax[w] = cmax;
    __syncthreads();
    const float mx = fmaxf(fmaxf(sWmax[0], sWmax[1]), fmaxf(sWmax[2], sWmax[3]));

    const float r    = rraw * L2E;                          // scaled domain
    const float smx  = r + mx;
    const float mhat = fmaxf(smx, LRELU_A * smx);           // >= every scaled e in row
    const float E1 = exp2f(r - mhat);
    const float E2 = exp2f(LRELU_A * r - mhat);
    f32x2 E1p; E1p.x = E1; E1p.y = E1;
    f32x2 E2p; E2p.x = E2; E2p.y = E2;
    float lsum = 0.f;

    const char* gBc = (const char*)(WhSw + (size_t)bt * 65536);
    const int slotoff = ((q + m15) & 3) * 16;               // XOR-swizzled slot

    f32x4 acc0 = 0.f, acc1 = 0.f, acc2 = 0.f, acc3 = 0.f;
    bf16x8 fA0, fA1, fA2, fA3;
    bf16x8 P0, P1, P2, P3, P4, P5, P6, P7;                  // bank P (32 VGPR)
    bf16x8 Q0, Q1, Q2, Q3, Q4, Q5, Q6, Q7;                  // bank Q (32 VGPR)

    LOAD8(P0, P1, P2, P3, P4, P5, P6, P7, 0, 0, 1);

    CHUNK_MID(0); CHUNK_MID(1); CHUNK_MID(2); CHUNK_MID(3);
    CHUNK_MID(4); CHUNK_MID(5); CHUNK_MID(6); CHUNK_LAST(7);

    // row denominators: lanes {l, l^16, l^32, l^48} share row m15
    lsum += __shfl_xor(lsum, 16, 64);
    lsum += __shfl_xor(lsum, 32, 64);

    const float rinv0 = 1.f / __shfl(lsum, q * 4 + 0, 64);
    const float rinv1 = 1.f / __shfl(lsum, q * 4 + 1, 64);
    const float rinv2 = 1.f / __shfl(lsum, q * 4 + 2, 64);
    const float rinv3 = 1.f / __shfl(lsum, q * 4 + 3, 64);

    EPI(0, acc0); EPI(1, acc1); EPI(2, acc2); EPI(3, acc3);
}

// ------------------------------------------------------------------
extern "C" void kernel_launch(void* const* d_in, const int* in_sizes, int n_in,
                              void* d_out, int out_size, void* d_ws, size_t ws_size,
                              hipStream_t stream)
{
    const float* x    = (const float*)d_in[0];
    const int*   adj  = (const int*)  d_in[1];
    const float* emb1 = (const float*)d_in[2];
    const float* emb2 = (const float*)d_in[3];
    const float* W    = (const float*)d_in[4];
    const float* a    = (const float*)d_in[5];
    const float* a2   = (const float*)d_in[6];
    float* out = (float*)d_out;

    unsigned short* WhSw = (unsigned short*)d_ws;             // 6.29 MB
    float* s1 = (float*)(WhSw + (size_t)BT * 65536);
    float* s2 = s1 + BT * N;
    float* f1 = s2 + BT * N;
    float* f2 = f1 + N;
    unsigned int* adjBits = (unsigned int*)(f2 + N);          // 128 KB

    hipLaunchKernelGGL(k_proj_misc, dim3(768), dim3(256), 0, stream,
                       x, W, a, adj, emb1, emb2, a2, WhSw, s1, s2, adjBits, f1, f2);
    hipLaunchKernelGGL(k_attn, dim3(BT * 16), dim3(256), 0, stream,
                       adjBits, WhSw, s1, s2, f1, f2, out);
}